// Round 14
// baseline (929.628 us; speedup 1.0000x reference)
//
#include <hip/hip_runtime.h>
#include <hip/hip_bf16.h>
#include <math.h>

// ---------- types ----------
typedef __attribute__((ext_vector_type(8))) short bf16x8;   // 8 bf16 in 4 VGPRs
typedef __attribute__((ext_vector_type(4))) float f32x4;

#define SCALE_QK 0.03608439182435162f   // 1/sqrt(768)

// ---------- helpers ----------
__device__ __forceinline__ unsigned short f2bf_rne(float f) {
    union { float f; unsigned u; } x; x.f = f;
    unsigned r = x.u + 0x7FFFu + ((x.u >> 16) & 1u);
    return (unsigned short)(r >> 16);
}
__device__ __forceinline__ void store4(unsigned short* p, float v0, float v1, float v2, float v3) {
    ushort4 o; o.x = f2bf_rne(v0); o.y = f2bf_rne(v1); o.z = f2bf_rne(v2); o.w = f2bf_rne(v3);
    *(ushort4*)p = o;
}
__device__ __forceinline__ void store4(float* p, float v0, float v1, float v2, float v3) {
    float4 o; o.x = v0; o.y = v1; o.z = v2; o.w = v3;
    *(float4*)p = o;
}
__device__ __forceinline__ void async_copy16(const void* g, void* l) {
    __builtin_amdgcn_global_load_lds(
        (const __attribute__((address_space(1))) void*)g,
        (__attribute__((address_space(3))) void*)l, 16, 0, 0);
}

// ---------- manual grid barrier (R14) ----------
// R13 post-mortem: absmax == max|ref| => cooperative launch never ran (capture
// or co-residency validation rejected it). This barrier needs NO cooperative
// API: regular launch; co-residency guaranteed by __launch_bounds__(256,3)
// (register cap) + 33792 B LDS x3 = 101 KB < 160 KB -> every CU takes exactly
// 3 blocks, 768 = 256x3 all resident. One-shot counter per phase boundary
// (memset to 0 per replay). release: __threadfence (L2 writeback at agent
// scope) + ACQ_REL RMW; acquire: ACQUIRE spin load + __threadfence (inv).
__device__ __forceinline__ void gridbar(int* bar, int G) {
    __syncthreads();                         // all block stores retired (vmcnt drained)
    if (threadIdx.x == 0) {
        __threadfence();                     // release: write back this XCD's L2
        __hip_atomic_fetch_add(bar, 1, __ATOMIC_ACQ_REL, __HIP_MEMORY_SCOPE_AGENT);
        while (__hip_atomic_load(bar, __ATOMIC_ACQUIRE, __HIP_MEMORY_SCOPE_AGENT) < G)
            __builtin_amdgcn_s_sleep(32);    // poll ~every 2k cycles
        __threadfence();                     // acquire: invalidate L1/L2
    }
    __syncthreads();
}

// ---------- shared 128x128 GEMM core (R0-proven 2-barrier loop) ----------
// R1-R3: every source-level async variant regressed; keep the 2-barrier loop.
// LDS XOR-swizzled 16B granules (conflict-free). MFMA operands swapped
// (D = B-frag x A-frag = C^T fragment) -> contiguous stores in epilogues.
__device__ __forceinline__ void gemm_core128(
    unsigned short* shA, unsigned short* shB,
    const unsigned short* __restrict__ A, int lda,
    const unsigned short* __restrict__ B, int ldb,
    long long tileM, long long tileN, int K,
    int t, int wm, int wn, int quad, int l16, f32x4 (&acc)[4][4])
{
    for (int k0 = 0; k0 < K; k0 += 64) {
        __syncthreads();
#pragma unroll
        for (int p = 0; p < 4; ++p) {
            const int g   = p * 256 + t;
            const int row = g >> 3;
            const int kg  = (g & 7) ^ (row & 7);
            async_copy16(A + (tileM + row) * (long long)lda + k0 + kg * 8, &shA[g << 3]);
            async_copy16(B + (tileN + row) * (long long)ldb + k0 + kg * 8, &shB[g << 3]);
        }
        __syncthreads();
#pragma unroll 1
        for (int h = 0; h < 2; ++h) {
            bf16x8 af[4], bfr[4];
#pragma unroll
            for (int mi = 0; mi < 4; ++mi) {
                const int row = wm + mi * 16 + l16;
                const int kg  = ((h << 2) | quad) ^ (row & 7);
                af[mi] = *(const bf16x8*)(&shA[row * 64 + kg * 8]);
            }
#pragma unroll
            for (int ni = 0; ni < 4; ++ni) {
                const int row = wn + ni * 16 + l16;
                const int kg  = ((h << 2) | quad) ^ (row & 7);
                bfr[ni] = *(const bf16x8*)(&shB[row * 64 + kg * 8]);
            }
#pragma unroll
            for (int mi = 0; mi < 4; ++mi)
#pragma unroll
                for (int ni = 0; ni < 4; ++ni)
                    acc[mi][ni] = __builtin_amdgcn_mfma_f32_16x16x32_bf16(
                        bfr[ni], af[mi], acc[mi][ni], 0, 0, 0);
        }
    }
}

// ================= phase bodies (verbatim R9-R12 math) =================

// ---- phase 1: prep (1212 virtual blocks) ----
__device__ __forceinline__ void prep_body(
    int blk, int t, unsigned short* sh,
    const float* __restrict__ w_qkv, const float* __restrict__ b_qkv,
    const float* __restrict__ w_out, const float* __restrict__ b_out,
    unsigned short* wqT, unsigned short* wkT, unsigned short* wvT,
    unsigned short* wob, float* v2f, float* bpp)
{
    __syncthreads();                                  // LDS reuse across virtual blocks
    if (blk < 432) {
        float (*shT)[65] = reinterpret_cast<float(*)[65]>(sh);   // 16640 B
        const int m  = blk / 144;
        const int r  = blk % 144;
        const int ty = r / 12;
        const int tx = r % 12;
        const float* W = w_qkv + (long long)m * 768 * 768;
        unsigned short* WT = (m == 0) ? wqT : (m == 1) ? wkT : wvT;
        const int il = t & 63;
        const int ob = t >> 6;
#pragma unroll
        for (int it = 0; it < 16; ++it) {
            const int ol = ob + it * 4;
            shT[ol][il] = W[(long long)(ty * 64 + ol) * 768 + tx * 64 + il];
        }
        __syncthreads();
#pragma unroll
        for (int it = 0; it < 16; ++it) {
            const int il2 = ob + it * 4;
            WT[(long long)(tx * 64 + il2) * 768 + ty * 64 + il] = f2bf_rne(shT[il][il2]);
        }
    } else if (blk < 624) {
        const int d = (blk - 432) * 4 + (t >> 6);
        const int l = t & 63;
        float s = 0.f;
        for (int o = l; o < 768; o += 64)
            s += w_out[(long long)d * 768 + o] * b_qkv[1536 + o];
        for (int off = 1; off < 64; off <<= 1) s += __shfl_xor(s, off);
        if (l == 0) bpp[d] = b_out[d] + s;
    } else if (blk < 636) {
        float* pvv = reinterpret_cast<float*>(reinterpret_cast<char*>(sh) + 16640); // 4x64
        const int i0   = (blk - 624) * 64;
        const int il   = t & 63;
        const int wave = t >> 6;
        const float* Wk = w_qkv + 768LL * 768;
        float a = 0.f;
        for (int o = wave * 192; o < wave * 192 + 192; ++o)
            a += Wk[(long long)o * 768 + i0 + il] * b_qkv[o];   // bq
        pvv[wave * 64 + il] = a;
        __syncthreads();
        if (t < 64) v2f[i0 + t] = pvv[t] + pvv[64 + t] + pvv[128 + t] + pvv[192 + t];
    } else {
        const int j = (blk - 636) * 256 + t;         // < 147456 exact
        float4 v = ((const float4*)w_out)[j];
        ushort4 o;
        o.x = f2bf_rne(v.x); o.y = f2bf_rne(v.y);
        o.z = f2bf_rne(v.z); o.w = f2bf_rne(v.w);
        ((ushort4*)wob)[j] = o;
    }
}

// ---- phase 2a: weight GEMMs (blocks 0..71): z=0: B2[0:768]=s*M^T ; z=1: W' ----
__device__ __forceinline__ void wgemm_body(
    int b, int t, unsigned short* sh,
    const unsigned short* wkT, const unsigned short* wqT,
    const unsigned short* wob, const unsigned short* wvT, unsigned short* B2)
{
    unsigned short* shA = sh;
    unsigned short* shB = sh + 8192;
    const int lane = t & 63;
    const int wave = t >> 6;
    const int wm   = (wave & 1) * 64;
    const int wn   = (wave >> 1) * 64;
    const int quad = lane >> 4;
    const int l16  = lane & 15;
    const int z  = b / 36;
    const int r  = b % 36;
    const long long tileM = (long long)(r / 6) * 128;
    const long long tileN = (long long)(r % 6) * 128;
    const unsigned short* A  = z ? wob : wkT;
    const unsigned short* Bp = z ? wvT : wqT;
    unsigned short* C = B2 + (long long)z * 768 * 768;
    const float sc = z ? 1.0f : SCALE_QK;   // bake QK scale into M

    f32x4 acc[4][4];
#pragma unroll
    for (int i = 0; i < 4; ++i)
#pragma unroll
        for (int j = 0; j < 4; ++j)
#pragma unroll
            for (int rr = 0; rr < 4; ++rr) acc[i][j][rr] = 0.0f;

    gemm_core128(shA, shB, A, 768, Bp, 768, tileM, tileN, 768, t, wm, wn, quad, l16, acc);

#pragma unroll
    for (int mi = 0; mi < 4; ++mi) {
        const long long gm = tileM + wm + mi * 16 + l16;
#pragma unroll
        for (int ni = 0; ni < 4; ++ni) {
            const long long gn0 = tileN + wn + ni * 16 + quad * 4;
            const f32x4 a = acc[mi][ni];
            store4(C + gm * 768 + gn0, a[0] * sc, a[1] * sc, a[2] * sc, a[3] * sc);
        }
    }
}

// ---- phase 2b: x convert + w dot (4096 units, 4 rows each) ----
__device__ __forceinline__ void cvtx_body(
    int u, int t,
    const float* __restrict__ x, unsigned short* xb,
    const float* __restrict__ v2f, float* wf)
{
    const int wave = t >> 6;
    const int lane = t & 63;
    const long long row = (long long)u * 4 + wave;
    const float4* xr = (const float4*)x + row * 192;
    ushort4* xbr = (ushort4*)xb + row * 192;
    const float4* v2 = (const float4*)v2f;
    float w = 0.f;
#pragma unroll
    for (int j = 0; j < 3; ++j) {
        const int c = j * 64 + lane;
        float4 v = xr[c];
        ushort4 o;
        o.x = f2bf_rne(v.x); o.y = f2bf_rne(v.y);
        o.z = f2bf_rne(v.z); o.w = f2bf_rne(v.w);
        xbr[c] = o;
        float4 b = v2[c];
        w += v.x * b.x + v.y * b.y + v.z * b.z + v.w * b.w;
    }
#pragma unroll
    for (int off = 1; off < 64; off <<= 1) w += __shfl_xor(w, off);
    if (lane == 0) wf[row] = w * SCALE_QK;
}

// ---- phase 3: x-GEMM tile (1536 tiles): xm cols 0..767, vwt transposed 768..1535 ----
__device__ __forceinline__ void xgemm_body(
    int tile, int t, unsigned short* sh,
    const unsigned short* xb, const unsigned short* B2,
    unsigned short* xm, unsigned short* vwt)
{
    unsigned short* shA = sh;
    unsigned short* shB = sh + 8448;
    const int lane = t & 63;
    const int wave = t >> 6;
    const int wm   = (wave & 1) * 64;
    const int wn   = (wave >> 1) * 64;
    const int quad = lane >> 4;
    const int l16  = lane & 15;
    const int bx = tile % 12;
    const int by = tile / 12;
    const long long tileM = (long long)by * 128;
    const long long tileN = (long long)bx * 128;

    f32x4 acc[4][4];
#pragma unroll
    for (int i = 0; i < 4; ++i)
#pragma unroll
        for (int j = 0; j < 4; ++j)
#pragma unroll
            for (int rr = 0; rr < 4; ++rr) acc[i][j][rr] = 0.0f;

    gemm_core128(shA, shB, xb, 768, B2, 768, tileM, tileN, 768, t, wm, wn, quad, l16, acc);

    const bool vt_block = (tileN >= 768);
    if (vt_block) __syncthreads();
    unsigned short* const shd = (wn == 0) ? shA : shB;   // pitch-132 d-major halves

#pragma unroll
    for (int mi = 0; mi < 4; ++mi) {
        const long long gm = tileM + wm + mi * 16 + l16;
#pragma unroll
        for (int ni = 0; ni < 4; ++ni) {
            const long long gn0 = tileN + wn + ni * 16 + quad * 4;
            const f32x4 a = acc[mi][ni];
            if (vt_block) {
                const int dl = (int)(ni * 16 + quad * 4);
                const int kl = wm + mi * 16 + l16;
                shd[(dl + 0) * 132 + kl] = f2bf_rne(a[0]);
                shd[(dl + 1) * 132 + kl] = f2bf_rne(a[1]);
                shd[(dl + 2) * 132 + kl] = f2bf_rne(a[2]);
                shd[(dl + 3) * 132 + kl] = f2bf_rne(a[3]);
            } else {
                store4(xm + gm * 768 + gn0, a[0], a[1], a[2], a[3]);
            }
        }
    }
    if (vt_block) {
        __syncthreads();
        const long long bvt  = tileM >> 10;
        const long long kin0 = tileM & 1023;
        const int dr = t >> 1;
        const int hf = t & 1;
        const unsigned short* src = (dr < 64) ? &shA[dr * 132] : &shB[(dr - 64) * 132];
        unsigned short* dst = vwt + (bvt * 768 + (tileN - 768) + dr) * 1024 + kin0 + hf * 64;
        src += hf * 64;
#pragma unroll
        for (int j = 0; j < 16; ++j)
            *(uint2*)(dst + j * 4) = *(const uint2*)(src + j * 4);
    }
}

// ---- phase 4: attn tile (1024 tiles, 128x128, R9-proven DO_EXP geometry) ----
// rpart slot (bx*2 + wn-half): 16 slots/row, each written exactly once (R8 lesson).
__device__ __forceinline__ void attn_body(
    int tile, int t, unsigned short* sh,
    const unsigned short* xm, const unsigned short* xb, unsigned short* att,
    const float* __restrict__ wf, float* rpart)
{
    unsigned short* shA = sh;
    unsigned short* shB = sh + 8192;
    const int lane = t & 63;
    const int wave = t >> 6;
    const int wm   = (wave & 1) * 64;
    const int wn   = (wave >> 1) * 64;
    const int quad = lane >> 4;
    const int l16  = lane & 15;
    const int bz = tile >> 6;          // tile = bz*64 + by*8 + bx
    const int by = (tile >> 3) & 7;
    const int bx = tile & 7;
    const unsigned short* A = xm + (long long)bz * 1024 * 768;
    const unsigned short* B = xb + (long long)bz * 1024 * 768;
    unsigned short* C = att + (long long)bz * 1024 * 1024;
    const long long tileM = (long long)by * 128;
    const long long tileN = (long long)bx * 128;

    f32x4 acc[4][4];
#pragma unroll
    for (int i = 0; i < 4; ++i)
#pragma unroll
        for (int j = 0; j < 4; ++j)
#pragma unroll
            for (int rr = 0; rr < 4; ++rr) acc[i][j][rr] = 0.0f;

    gemm_core128(shA, shB, A, 768, B, 768, tileM, tileN, 768, t, wm, wn, quad, l16, acc);

    const float* wfb = wf + (long long)bz * 1024;
    float wkv[4][4];
#pragma unroll
    for (int ni = 0; ni < 4; ++ni) {
        const long long gn0 = tileN + wn + ni * 16 + quad * 4;
        float4 t4 = *(const float4*)&wfb[gn0];
        wkv[ni][0] = t4.x; wkv[ni][1] = t4.y; wkv[ni][2] = t4.z; wkv[ni][3] = t4.w;
    }
#pragma unroll
    for (int mi = 0; mi < 4; ++mi) {
        const long long gm = tileM + wm + mi * 16 + l16;
        float rsum = 0.0f;
#pragma unroll
        for (int ni = 0; ni < 4; ++ni) {
            const long long gn0 = tileN + wn + ni * 16 + quad * 4;
            const f32x4 a = acc[mi][ni];
            const float v0 = __expf(a[0] + wkv[ni][0]);
            const float v1 = __expf(a[1] + wkv[ni][1]);
            const float v2 = __expf(a[2] + wkv[ni][2]);
            const float v3 = __expf(a[3] + wkv[ni][3]);
            rsum += (v0 + v1) + (v2 + v3);
            store4(C + gm * 1024 + gn0, v0, v1, v2, v3);
        }
        rsum += __shfl_xor(rsum, 16);
        rsum += __shfl_xor(rsum, 32);
        if (quad == 0) {
            const long long slot = (long long)(bx * 2 + (wn >> 6));
            rpart[(slot * 16 + bz) * 1024 + gm] = rsum;
        }
    }
}

// ---- phase 5: PV tile (768 tiles): out = (att @ vwt^T)/rowsum + b'' ----
__device__ __forceinline__ void pv_body(
    int tile, int t, unsigned short* sh,
    const unsigned short* att, const unsigned short* vwt, float* out,
    const float* __restrict__ bpp, const float* __restrict__ rpart)
{
    unsigned short* shA = sh;
    unsigned short* shB = sh + 8192;
    const int lane = t & 63;
    const int wave = t >> 6;
    const int wm   = (wave & 1) * 64;
    const int wn   = (wave >> 1) * 64;
    const int quad = lane >> 4;
    const int l16  = lane & 15;
    const int bx = tile % 6;           // d-tile
    const int rem = tile / 6;
    const int by = rem & 7;            // q-tile
    const int bz = rem >> 3;           // batch
    const unsigned short* A = att + (long long)bz * 1024 * 1024;
    const unsigned short* B = vwt + (long long)bz * 768 * 1024;
    float* C = out + (long long)bz * 1024 * 768;
    const long long tileM = (long long)by * 128;
    const long long tileN = (long long)bx * 128;

    f32x4 acc[4][4];
#pragma unroll
    for (int i = 0; i < 4; ++i)
#pragma unroll
        for (int j = 0; j < 4; ++j)
#pragma unroll
            for (int rr = 0; rr < 4; ++rr) acc[i][j][rr] = 0.0f;

    gemm_core128(shA, shB, A, 1024, B, 1024, tileM, tileN, 1024, t, wm, wn, quad, l16, acc);

#pragma unroll
    for (int mi = 0; mi < 4; ++mi) {
        const long long gm = tileM + wm + mi * 16 + l16;
        float s = 0.f;
#pragma unroll
        for (int j = 0; j < 16; ++j)
            s += rpart[((long long)j * 16 + bz) * 1024 + gm];
        const float w = 1.0f / s;
#pragma unroll
        for (int ni = 0; ni < 4; ++ni) {
            const long long gn0 = tileN + wn + ni * 16 + quad * 4;
            float4 bv = *(const float4*)&bpp[gn0];
            const f32x4 a = acc[mi][ni];
            store4(C + gm * 768 + gn0,
                   a[0] * w + bv.x, a[1] * w + bv.y, a[2] * w + bv.z, a[3] * w + bv.w);
        }
    }
}

// ================= mega kernel: 5 phases, one REGULAR launch =================
// R14: single dispatch removes the ~10-13 us/boundary overhead of the 5-launch
// chain (wall - sum(kernels) ~ 50-80 us, consistent across R0-R12). Manual
// device-scope barrier (gridbar) replaces grid.sync — no cooperative API.
// Co-residency by construction: __launch_bounds__(256,3) register cap + 33792 B
// LDS -> exactly 3 blocks/CU, 768 = 256 CUs x 3 all resident, spin cannot
// deadlock. Phase work XCD-chunked (b&7) for L2 locality, as in R12's swizzles.
__global__ __launch_bounds__(256, 3) void mega(
    const float* __restrict__ x, const float* __restrict__ w_qkv,
    const float* __restrict__ b_qkv, const float* __restrict__ w_out,
    const float* __restrict__ b_out, float* __restrict__ out,
    unsigned short* __restrict__ ws)
{
    __shared__ unsigned short sh[16896];   // 33792 B, carved per phase

    const int t = threadIdx.x;
    const int b = blockIdx.x;
    const int G = gridDim.x;               // 768
    const int x8 = b & 7;                  // XCD chunk id
    const int j8 = b >> 3;                 // index within chunk (0..95)
    const int C8 = G >> 3;                 // 96 blocks per chunk

    // workspace layout (matches launcher)
    const long long MS = 16384;
    unsigned short* xb  = ws;
    unsigned short* wob = xb  + MS * 768;
    unsigned short* wqT = wob + 768LL * 768;
    unsigned short* wkT = wqT + 768LL * 768;
    unsigned short* wvT = wkT + 768LL * 768;
    unsigned short* B2  = wvT + 768LL * 768;
    unsigned short* xm  = B2  + 1536LL * 768;
    unsigned short* vwt = xm  + MS * 768;
    unsigned short* att = vwt + 16LL * 768 * 1024;
    float* rpart = (float*)(att + 16LL * 1024 * 1024);   // [16][16][1024]
    float* v2f   = rpart + 16 * MS;
    float* bpp   = v2f + 768;
    float* wf    = bpp + 768;
    int*   bar   = (int*)(wf + MS);        // 4 one-shot phase counters (memset 0)

    // ---- phase 1: prep ----
    for (int vb = b; vb < 1212; vb += G)
        prep_body(vb, t, sh, w_qkv, b_qkv, w_out, b_out,
                  wqT, wkT, wvT, wob, v2f, bpp);
    gridbar(bar + 0, G);

    // ---- phase 2: weight GEMMs (blocks 0..71) || x convert + w dot ----
    if (b < 72) {
        wgemm_body(b, t, sh, wkT, wqT, wob, wvT, B2);
    } else {
        for (int u = b - 72; u < 4096; u += G - 72)
            cvtx_body(u, t, x, xb, v2f, wf);
    }
    gridbar(bar + 1, G);

    // ---- phase 3: x-GEMM, 1536 tiles XCD-chunked ----
    for (int k = 0;; ++k) {
        const int off = j8 + k * C8;
        if (off >= 192) break;
        xgemm_body(x8 * 192 + off, t, sh, xb, B2, xm, vwt);
    }
    gridbar(bar + 2, G);

    // ---- phase 4: attn, 1024 tiles XCD-chunked ----
    for (int k = 0;; ++k) {
        const int off = j8 + k * C8;
        if (off >= 128) break;
        attn_body(x8 * 128 + off, t, sh, xm, xb, att, wf, rpart);
    }
    gridbar(bar + 3, G);

    // ---- phase 5: PV, 768 tiles XCD-chunked ----
    for (int k = 0;; ++k) {
        const int off = j8 + k * C8;
        if (off >= 96) break;
        pv_body(x8 * 96 + off, t, sh, att, vwt, out, bpp, rpart);
    }
}

// ---------- launcher ----------
// R14 pipeline: memset(4 counters) + ONE regular 768-block launch.
// Math identical to R12 (attn 128x128 / 16 rpart slots).
extern "C" void kernel_launch(void* const* d_in, const int* in_sizes, int n_in,
                              void* d_out, int out_size, void* d_ws, size_t ws_size,
                              hipStream_t stream) {
    (void)in_sizes; (void)n_in; (void)out_size; (void)ws_size;

    const float* x     = (const float*)d_in[0];
    const float* w_qkv = (const float*)d_in[1];
    const float* b_qkv = (const float*)d_in[2];
    const float* w_out = (const float*)d_in[3];
    const float* b_out = (const float*)d_in[4];
    float* out = (float*)d_out;
    unsigned short* ws = (unsigned short*)d_ws;

    // barrier counters live after wf in the workspace (see mega's layout)
    const long long MS = 16384;
    unsigned short* xb  = ws;
    unsigned short* wob = xb  + MS * 768;
    unsigned short* B2  = wob + 4LL * 768 * 768;        // wob + wqT + wkT + wvT
    unsigned short* xm  = B2  + 1536LL * 768;
    unsigned short* vwt = xm  + MS * 768;
    unsigned short* att = vwt + 16LL * 768 * 1024;
    float* rpart = (float*)(att + 16LL * 1024 * 1024);
    float* wf    = rpart + 16 * MS + 768 + 768;
    int*   bar   = (int*)(wf + MS);

    hipMemsetAsync(bar, 0, 4 * sizeof(int), stream);
    mega<<<768, 256, 0, stream>>>(x, w_qkv, b_qkv, w_out, b_out, out, ws);
}